// Round 1
// 2898.971 us; speedup vs baseline: 1.0636x; 1.0636x over previous
//
#include <hip/hip_runtime.h>
#include <stdint.h>

#define Vv 10000
#define Ee 1024
#define Hh 1024
#define Ll 2
#define Ss 128
#define Bb 64
#define NPAD 10112  // 79 * 128

typedef __attribute__((ext_vector_type(8))) short short8v;
typedef __attribute__((ext_vector_type(4))) float float4v;
typedef __attribute__((ext_vector_type(4))) unsigned short ushort4v;
typedef unsigned long long ull;

__device__ __forceinline__ unsigned short f2bf(float x) {
  union { float f; unsigned u; } v; v.f = x;
  unsigned r = v.u + 0x7fffu + ((v.u >> 16) & 1u);  // RNE
  return (unsigned short)(r >> 16);
}
__device__ __forceinline__ ushort4v cvt4(float4v v, float s) {
  ushort4v r;
  r.x = f2bf(v.x * s); r.y = f2bf(v.y * s); r.z = f2bf(v.z * s); r.w = f2bf(v.w * s);
  return r;
}
__device__ __forceinline__ float fast_tanh(float x) {
  float e = __expf(2.0f * x);          // saturates correctly at +/-inf
  return 1.0f - 2.0f / (e + 1.0f);
}
__device__ __forceinline__ void gload_lds16(const void* g, void* l) {
  __builtin_amdgcn_global_load_lds((const __attribute__((address_space(1))) void*)g,
                                   (__attribute__((address_space(3))) void*)l, 16, 0, 0);
}
__device__ __forceinline__ ull ald(const ull* p) {
  return __hip_atomic_load(p, __ATOMIC_RELAXED, __HIP_MEMORY_SCOPE_AGENT);
}
__device__ __forceinline__ void ast(ull* p, ull v) {
  __hip_atomic_store(p, v, __ATOMIC_RELAXED, __HIP_MEMORY_SCOPE_AGENT);
}
__device__ __forceinline__ unsigned fld(const unsigned* p) {
  return __hip_atomic_load(p, __ATOMIC_RELAXED, __HIP_MEMORY_SCOPE_AGENT);
}
__device__ __forceinline__ void fst(unsigned* p, unsigned v) {
  __hip_atomic_store(p, v, __ATOMIC_RELAXED, __HIP_MEMORY_SCOPE_AGENT);
}

// ---------------- W_out fp32 -> bf16, padded to NPAD rows ----------------
extern "C" __global__ void k_conv_wout(const float* __restrict__ w,
                                       unsigned short* __restrict__ dst) {
  const int r = blockIdx.x;
  const int c = threadIdx.x * 4;
  ushort4v o;
  if (r < Vv) {
    float4v v = *reinterpret_cast<const float4v*>(w + (size_t)r * Hh + c);
    o = cvt4(v, 1.0f);
  } else {
    o.x = 0; o.y = 0; o.z = 0; o.w = 0;
  }
  *reinterpret_cast<ushort4v*>(dst + (size_t)r * Hh + c) = o;
}

// ---------------- pre0[m][n] = (emb[tok[m]]*32) @ W_ih0^T  (no bias) ----------------
extern "C" __global__ void __launch_bounds__(256) k_gemm_pre0(
    const int* __restrict__ tok, const float* __restrict__ emb,
    const float* __restrict__ wih0, float* __restrict__ pre0) {
  __shared__ unsigned short As[128 * 32];
  __shared__ unsigned short Bs[128 * 32];
  const int m0 = blockIdx.x * 128;
  const int n0 = blockIdx.y * 128;
  const int tid = threadIdx.x;
  const int lane = tid & 63;
  const int wv = tid >> 6;
  const int wm = wv & 1, wn = wv >> 1;
  float4v acc[4][4] = {};
  for (int k0 = 0; k0 < Ee; k0 += 32) {
    __syncthreads();
#pragma unroll
    for (int i = 0; i < 4; ++i) {  // stage 128x32 bf16 tiles, convert on the fly
      int c = i * 256 + tid;       // 0..1023 chunks of 4 elems
      int r = c >> 3, q = c & 7;
      int tk = tok[m0 + r];
      float4v va = *reinterpret_cast<const float4v*>(emb + (size_t)tk * Ee + k0 + q * 4);
      *reinterpret_cast<ushort4v*>(&As[c * 4]) = cvt4(va, 32.0f);  // sqrt(1024)=32
      float4v vb = *reinterpret_cast<const float4v*>(wih0 + (size_t)(n0 + r) * Ee + k0 + q * 4);
      *reinterpret_cast<ushort4v*>(&Bs[c * 4]) = cvt4(vb, 1.0f);
    }
    __syncthreads();
    short8v af[4], bf[4];
#pragma unroll
    for (int i = 0; i < 4; ++i) {
      af[i] = *reinterpret_cast<const short8v*>(&As[(wm * 64 + i * 16 + (lane & 15)) * 32 + (lane >> 4) * 8]);
      bf[i] = *reinterpret_cast<const short8v*>(&Bs[(wn * 64 + i * 16 + (lane & 15)) * 32 + (lane >> 4) * 8]);
    }
#pragma unroll
    for (int mi = 0; mi < 4; ++mi)
#pragma unroll
      for (int ni = 0; ni < 4; ++ni)
        acc[mi][ni] = __builtin_amdgcn_mfma_f32_16x16x32_bf16(af[mi], bf[ni], acc[mi][ni], 0, 0, 0);
  }
#pragma unroll
  for (int mi = 0; mi < 4; ++mi) {
    const int rb = m0 + wm * 64 + mi * 16 + ((lane >> 4) << 2);
#pragma unroll
    for (int ni = 0; ni < 4; ++ni) {
      const int col = n0 + wn * 64 + ni * 16 + (lane & 15);
#pragma unroll
      for (int r = 0; r < 4; ++r)
        pre0[(size_t)(rb + r) * Hh + col] = acc[mi][ni][r];
    }
  }
}

// ---------------- fused pipelined 2-layer recurrence (fence-free) ----------------
// blocks 0..63: layer0 (cols j*16..); blocks 64..127: layer1 (1 step behind).
// X layout: [slot][b][col] bf16; slot 0 = initial hidden, slot t+1 = h after step t.
// All cross-block traffic via relaxed agent-scope atomics (bypass non-coherent L2).
// Sync redesign vs previous version (contention fix):
//   - ONE flag per (layer, slot, block): flags[(layer*(Ss+1)+slot)*64 + j].
//     Producer: all waves store data -> __syncthreads (drains vmcnt) -> tid0 flag.
//   - ONLY wave 0 polls (64 lanes cover all 64 producer flags in one load),
//     with s_sleep backoff; waves 1..3 wait at __syncthreads.
//   Cuts flag-line requests at the coherence point ~20x so producer flag stores
//   are not queued behind spinning pollers.
extern "C" __global__ void __launch_bounds__(256) k_chain(
    const float* __restrict__ whh, const float* __restrict__ wih,
    const float* __restrict__ bih, const float* __restrict__ bhh,
    const float* __restrict__ hidden, const float* __restrict__ pre0,
    unsigned short* __restrict__ X0, unsigned short* __restrict__ X1,
    unsigned int* flags, float* __restrict__ hfin) {
  __shared__ unsigned short Wxs[16 * 1024];  // layer1 W_ih slice (XOR-swizzled)
  const int layer = blockIdx.x >> 6;
  const int j = blockIdx.x & 63;
  const int c0 = j * 16;
  const int tid = threadIdx.x;
  const int lane = tid & 63;
  const int wv = tid >> 6;
  const int m = lane & 15;        // A-frag row (weight out-col); B-frag row (batch)
  const int q = lane >> 4;        // quad -> k-chunk / C-row group
  const int brow = wv * 16 + m;   // batch row this lane loads/stores
  const int csub = q * 4;         // 4 consecutive output cols per lane (C rows)

  // ---- hoist recurrent-W A-fragments into registers (step-invariant) ----
  short8v afr[32];
  {
    const float* wrec = whh + (size_t)layer * Hh * Hh + (size_t)(c0 + m) * Hh + q * 8;
#pragma unroll
    for (int kt = 0; kt < 32; ++kt) {
      union { ushort4v h[2]; short8v v; } u;
      float4v w0 = *reinterpret_cast<const float4v*>(wrec + kt * 32);
      float4v w1 = *reinterpret_cast<const float4v*>(wrec + kt * 32 + 4);
      u.h[0] = cvt4(w0, 1.0f); u.h[1] = cvt4(w1, 1.0f);
      afr[kt] = u.v;
    }
  }
  // ---- layer1: stage W_ih slice in LDS (swizzle: 2-way banks, free) ----
  if (layer) {
#pragma unroll
    for (int i = 0; i < 8; ++i) {
      int c = i * 256 + tid;  // 2048 chunks of 8 elems
      int row = c >> 7, qq = c & 127;
      int p = (qq & ~7) | ((qq ^ row) & 7);
      const float* sx = wih + (size_t)Hh * Ee + (size_t)(c0 + row) * Ee + qq * 8;
      float4v u0 = *reinterpret_cast<const float4v*>(sx);
      float4v u1 = *reinterpret_cast<const float4v*>(sx + 4);
      *reinterpret_cast<ushort4v*>(&Wxs[row * 1024 + p * 8]) = cvt4(u0, 1.0f);
      *reinterpret_cast<ushort4v*>(&Wxs[row * 1024 + p * 8 + 4]) = cvt4(u1, 1.0f);
    }
  }
  __syncthreads();

  float4v bias4;
  {
    float4v b1 = *reinterpret_cast<const float4v*>(bih + (size_t)layer * Hh + c0 + csub);
    float4v b2 = *reinterpret_cast<const float4v*>(bhh + (size_t)layer * Hh + c0 + csub);
    bias4 = b1 + b2;
  }
  unsigned short* Xown = layer ? X1 : X0;

  // ---- init slot 0 from `hidden` ----
  {
    float4v h0 = *reinterpret_cast<const float4v*>(hidden + ((size_t)layer * Bb + brow) * Hh + c0 + csub);
    ull pk = (ull)f2bf(h0.x) | ((ull)f2bf(h0.y) << 16) | ((ull)f2bf(h0.z) << 32) | ((ull)f2bf(h0.w) << 48);
    ast((ull*)(Xown + (size_t)brow * Hh + c0 + csub), pk);
  }
  asm volatile("s_waitcnt vmcnt(0)" ::: "memory");
  __syncthreads();  // all 4 waves' slot-0 stores drained
  if (tid == 0)
    fst(&flags[((size_t)layer * (Ss + 1)) * 64 + j], 1u);

  for (int t = 0; t < Ss; ++t) {
    // ---- wave 0 polls producer flags (with backoff); others wait at barrier ----
    if (wv == 0) {
      if (layer == 0) {
        const unsigned* f = flags + (size_t)t * 64;
        int sp = 0;
        for (;;) {
          unsigned v = fld(&f[lane]);
          if (!__any(v == 0)) break;
          if (++sp > (1 << 20)) break;
          __builtin_amdgcn_s_sleep(2);
        }
      } else {
        const unsigned* fa = flags + (size_t)(t + 1) * 64;               // layer0 slot t+1
        const unsigned* fb = flags + ((size_t)(Ss + 1) + t) * 64;        // layer1 slot t
        int sp = 0;
        for (;;) {
          unsigned va = fld(&fa[lane]);
          unsigned vb = fld(&fb[lane]);
          if (!__any((va == 0) | (vb == 0))) break;
          if (++sp > (1 << 20)) break;
          __builtin_amdgcn_s_sleep(2);
        }
      }
    }
    __syncthreads();                // release waves 1..3 once flags observed
    asm volatile("" ::: "memory");  // keep data loads after the poll/barrier

    const ull* p0 = (const ull*)((layer ? X0 + (size_t)(t + 1) * Bb * Hh
                                        : X0 + (size_t)t * Bb * Hh) + (size_t)brow * Hh) + q * 2;
    const ull* p1 = (const ull*)(X1 + ((size_t)t * Bb + brow) * Hh) + q * 2;

    float4v acc0 = {0.f, 0.f, 0.f, 0.f}, acc1 = {0.f, 0.f, 0.f, 0.f};
    if (layer == 0) {
#pragma unroll
      for (int kt = 0; kt < 32; kt += 2) {
        union { ull u[2]; short8v v; } b0, b1;
        b0.u[0] = ald(p0 + kt * 8);
        b0.u[1] = ald(p0 + kt * 8 + 1);
        b1.u[0] = ald(p0 + kt * 8 + 8);
        b1.u[1] = ald(p0 + kt * 8 + 9);
        acc0 = __builtin_amdgcn_mfma_f32_16x16x32_bf16(afr[kt], b0.v, acc0, 0, 0, 0);
        acc1 = __builtin_amdgcn_mfma_f32_16x16x32_bf16(afr[kt + 1], b1.v, acc1, 0, 0, 0);
      }
    } else {
#pragma unroll
      for (int kt = 0; kt < 32; ++kt) {
        union { ull u[2]; short8v v; } b0, b1;
        b0.u[0] = ald(p0 + kt * 8);
        b0.u[1] = ald(p0 + kt * 8 + 1);
        b1.u[0] = ald(p1 + kt * 8);
        b1.u[1] = ald(p1 + kt * 8 + 1);
        int qc = kt * 4 + q;
        int p8 = ((qc & ~7) | ((qc ^ m) & 7)) * 8;
        short8v ax = *reinterpret_cast<const short8v*>(&Wxs[m * 1024 + p8]);
        acc0 = __builtin_amdgcn_mfma_f32_16x16x32_bf16(ax, b0.v, acc0, 0, 0, 0);       // W_ih @ x
        acc1 = __builtin_amdgcn_mfma_f32_16x16x32_bf16(afr[kt], b1.v, acc1, 0, 0, 0);  // W_hh @ h
      }
    }

    float4v r = acc0 + acc1 + bias4;
    if (layer == 0) {
      float4v pz = *reinterpret_cast<const float4v*>(pre0 + ((size_t)t * Bb + brow) * Hh + c0 + csub);
      r += pz;
    }
    float h0 = fast_tanh(r.x), h1 = fast_tanh(r.y), h2 = fast_tanh(r.z), h3 = fast_tanh(r.w);
    if (t == Ss - 1) {
      float4v hf = {h0, h1, h2, h3};
      *reinterpret_cast<float4v*>(hfin + ((size_t)layer * Bb + brow) * Hh + c0 + csub) = hf;
    }
    ull pk = (ull)f2bf(h0) | ((ull)f2bf(h1) << 16) | ((ull)f2bf(h2) << 32) | ((ull)f2bf(h3) << 48);
    ast((ull*)(Xown + ((size_t)(t + 1) * Bb + brow) * Hh + c0 + csub), pk);
    asm volatile("s_waitcnt vmcnt(0)" ::: "memory");  // data at coherence point
    __syncthreads();                                  // ... for ALL waves of the block
    if (tid == 0)
      fst(&flags[((size_t)layer * (Ss + 1) + (t + 1)) * 64 + j], 1u);
  }
}

// ---------------- logits = X1 @ Wout^T + b_out ----------------
extern "C" __global__ void __launch_bounds__(256) k_gemm_logits(
    const unsigned short* __restrict__ Abf, const unsigned short* __restrict__ Bbf,
    const float* __restrict__ bout, float* __restrict__ out) {
  __shared__ unsigned short As[128 * 32];
  __shared__ unsigned short Bs[128 * 32];
  const int m0 = blockIdx.x * 128;
  const int n0 = blockIdx.y * 128;
  const int tid = threadIdx.x;
  const int lane = tid & 63;
  const int wv = tid >> 6;
  const int wm = wv & 1, wn = wv >> 1;
  float4v acc[4][4] = {};
  for (int k0 = 0; k0 < Hh; k0 += 32) {
    __syncthreads();
#pragma unroll
    for (int i = 0; i < 2; ++i) {  // async stage 16B/lane; base wave-uniform
      int c = (wv * 2 + i) * 64 + lane;  // 0..511 chunks of 8 elems
      int r = c >> 2, q = c & 3;
      gload_lds16(Abf + (size_t)(m0 + r) * Hh + k0 + q * 8, &As[(wv * 2 + i) * 512]);
      gload_lds16(Bbf + (size_t)(n0 + r) * Hh + k0 + q * 8, &Bs[(wv * 2 + i) * 512]);
    }
    __syncthreads();
    short8v af[4], bf[4];
#pragma unroll
    for (int i = 0; i < 4; ++i) {
      af[i] = *reinterpret_cast<const short8v*>(&As[(wm * 64 + i * 16 + (lane & 15)) * 32 + (lane >> 4) * 8]);
      bf[i] = *reinterpret_cast<const short8v*>(&Bs[(wn * 64 + i * 16 + (lane & 15)) * 32 + (lane >> 4) * 8]);
    }
#pragma unroll
    for (int mi = 0; mi < 4; ++mi)
#pragma unroll
      for (int ni = 0; ni < 4; ++ni)
        acc[mi][ni] = __builtin_amdgcn_mfma_f32_16x16x32_bf16(af[mi], bf[ni], acc[mi][ni], 0, 0, 0);
  }
#pragma unroll
  for (int mi = 0; mi < 4; ++mi) {
    const int rb = m0 + wm * 64 + mi * 16 + ((lane >> 4) << 2);
#pragma unroll
    for (int ni = 0; ni < 4; ++ni) {
      const int col = n0 + wn * 64 + ni * 16 + (lane & 15);
      if (col < Vv) {
        const float bz = bout[col];
#pragma unroll
        for (int r = 0; r < 4; ++r)
          out[(size_t)(rb + r) * Vv + col] = acc[mi][ni][r] + bz;
      }
    }
  }
}

extern "C" void kernel_launch(void* const* d_in, const int* in_sizes, int n_in,
                              void* d_out, int out_size, void* d_ws, size_t ws_size,
                              hipStream_t stream) {
  (void)in_sizes; (void)n_in; (void)out_size; (void)ws_size;
  const int* tok = (const int*)d_in[0];
  const float* hidden = (const float*)d_in[1];
  const float* emb = (const float*)d_in[2];
  const float* wih = (const float*)d_in[3];
  const float* bih = (const float*)d_in[4];
  const float* whh = (const float*)d_in[5];
  const float* bhh = (const float*)d_in[6];
  const float* wout = (const float*)d_in[7];
  const float* bout = (const float*)d_in[8];
  float* out = (float*)d_out;

  char* ws = (char*)d_ws;
  size_t off = 0;
  auto walloc = [&](size_t b) { void* p = ws + off; off = (off + b + 255) & ~(size_t)255; return p; };
  unsigned short* X0 = (unsigned short*)walloc((size_t)(Ss + 1) * Bb * Hh * 2);  // 16.9 MB
  unsigned short* X1 = (unsigned short*)walloc((size_t)(Ss + 1) * Bb * Hh * 2);  // 16.9 MB
  float* pre0 = (float*)walloc((size_t)Ss * Bb * Hh * 4);                        // 33.6 MB
  unsigned short* wob = (unsigned short*)walloc((size_t)NPAD * Hh * 2);          // 20.7 MB
  const size_t flag_bytes = (size_t)2 * (Ss + 1) * 64 * 4;                       // 66 KB
  unsigned int* flags = (unsigned int*)walloc(flag_bytes);

  hipMemsetAsync(flags, 0, flag_bytes, stream);  // ws is poisoned 0xAA each run
  k_conv_wout<<<NPAD, 256, 0, stream>>>(wout, wob);
  k_gemm_pre0<<<dim3(64, 8), 256, 0, stream>>>(tok, emb, wih, pre0);
  k_chain<<<128, 256, 0, stream>>>(whh, wih, bih, bhh, hidden, pre0, X0, X1, flags,
                                   out + (size_t)Ss * Bb * Vv);
  k_gemm_logits<<<dim3(64, 79), 256, 0, stream>>>(X1 + (size_t)Bb * Hh, wob, bout, out);
}

// Round 2
// 1975.118 us; speedup vs baseline: 1.5611x; 1.4677x over previous
//
#include <hip/hip_runtime.h>
#include <stdint.h>

#define Vv 10000
#define Ee 1024
#define Hh 1024
#define Ll 2
#define Ss 128
#define Bb 64
#define NPAD 10112  // 79 * 128

typedef __attribute__((ext_vector_type(8))) short short8v;
typedef __attribute__((ext_vector_type(4))) float float4v;
typedef __attribute__((ext_vector_type(4))) unsigned short ushort4v;
typedef unsigned long long ull;

__device__ __forceinline__ unsigned short f2bf(float x) {
  union { float f; unsigned u; } v; v.f = x;
  unsigned r = v.u + 0x7fffu + ((v.u >> 16) & 1u);  // RNE
  return (unsigned short)(r >> 16);
}
__device__ __forceinline__ ushort4v cvt4(float4v v, float s) {
  ushort4v r;
  r.x = f2bf(v.x * s); r.y = f2bf(v.y * s); r.z = f2bf(v.z * s); r.w = f2bf(v.w * s);
  return r;
}
__device__ __forceinline__ float fast_tanh(float x) {
  float e = __expf(2.0f * x);          // saturates correctly at +/-inf
  return 1.0f - 2.0f / (e + 1.0f);
}
__device__ __forceinline__ void gload_lds16(const void* g, void* l) {
  __builtin_amdgcn_global_load_lds((const __attribute__((address_space(1))) void*)g,
                                   (__attribute__((address_space(3))) void*)l, 16, 0, 0);
}
__device__ __forceinline__ ull ald(const ull* p) {
  return __hip_atomic_load(p, __ATOMIC_RELAXED, __HIP_MEMORY_SCOPE_AGENT);
}
__device__ __forceinline__ void ast(ull* p, ull v) {
  __hip_atomic_store(p, v, __ATOMIC_RELAXED, __HIP_MEMORY_SCOPE_AGENT);
}
__device__ __forceinline__ unsigned fld(const unsigned* p) {
  return __hip_atomic_load(p, __ATOMIC_RELAXED, __HIP_MEMORY_SCOPE_AGENT);
}
__device__ __forceinline__ void fst(unsigned* p, unsigned v) {
  __hip_atomic_store(p, v, __ATOMIC_RELAXED, __HIP_MEMORY_SCOPE_AGENT);
}

// ---------------- W_out fp32 -> bf16, padded to NPAD rows ----------------
extern "C" __global__ void k_conv_wout(const float* __restrict__ w,
                                       unsigned short* __restrict__ dst) {
  const int r = blockIdx.x;
  const int c = threadIdx.x * 4;
  ushort4v o;
  if (r < Vv) {
    float4v v = *reinterpret_cast<const float4v*>(w + (size_t)r * Hh + c);
    o = cvt4(v, 1.0f);
  } else {
    o.x = 0; o.y = 0; o.z = 0; o.w = 0;
  }
  *reinterpret_cast<ushort4v*>(dst + (size_t)r * Hh + c) = o;
}

// ---------------- pre0[m][n] = (emb[tok[m]]*32) @ W_ih0^T  (no bias) ----------------
extern "C" __global__ void __launch_bounds__(256) k_gemm_pre0(
    const int* __restrict__ tok, const float* __restrict__ emb,
    const float* __restrict__ wih0, float* __restrict__ pre0) {
  __shared__ unsigned short As[128 * 32];
  __shared__ unsigned short Bs[128 * 32];
  const int m0 = blockIdx.x * 128;
  const int n0 = blockIdx.y * 128;
  const int tid = threadIdx.x;
  const int lane = tid & 63;
  const int wv = tid >> 6;
  const int wm = wv & 1, wn = wv >> 1;
  float4v acc[4][4] = {};
  for (int k0 = 0; k0 < Ee; k0 += 32) {
    __syncthreads();
#pragma unroll
    for (int i = 0; i < 4; ++i) {  // stage 128x32 bf16 tiles, convert on the fly
      int c = i * 256 + tid;       // 0..1023 chunks of 4 elems
      int r = c >> 3, q = c & 7;
      int tk = tok[m0 + r];
      float4v va = *reinterpret_cast<const float4v*>(emb + (size_t)tk * Ee + k0 + q * 4);
      *reinterpret_cast<ushort4v*>(&As[c * 4]) = cvt4(va, 32.0f);  // sqrt(1024)=32
      float4v vb = *reinterpret_cast<const float4v*>(wih0 + (size_t)(n0 + r) * Ee + k0 + q * 4);
      *reinterpret_cast<ushort4v*>(&Bs[c * 4]) = cvt4(vb, 1.0f);
    }
    __syncthreads();
    short8v af[4], bf[4];
#pragma unroll
    for (int i = 0; i < 4; ++i) {
      af[i] = *reinterpret_cast<const short8v*>(&As[(wm * 64 + i * 16 + (lane & 15)) * 32 + (lane >> 4) * 8]);
      bf[i] = *reinterpret_cast<const short8v*>(&Bs[(wn * 64 + i * 16 + (lane & 15)) * 32 + (lane >> 4) * 8]);
    }
#pragma unroll
    for (int mi = 0; mi < 4; ++mi)
#pragma unroll
      for (int ni = 0; ni < 4; ++ni)
        acc[mi][ni] = __builtin_amdgcn_mfma_f32_16x16x32_bf16(af[mi], bf[ni], acc[mi][ni], 0, 0, 0);
  }
#pragma unroll
  for (int mi = 0; mi < 4; ++mi) {
    const int rb = m0 + wm * 64 + mi * 16 + ((lane >> 4) << 2);
#pragma unroll
    for (int ni = 0; ni < 4; ++ni) {
      const int col = n0 + wn * 64 + ni * 16 + (lane & 15);
#pragma unroll
      for (int r = 0; r < 4; ++r)
        pre0[(size_t)(rb + r) * Hh + col] = acc[mi][ni][r];
    }
  }
}

// ---- pipelined register-buffer helpers (static indexing only; rule #20) ----
__device__ __forceinline__ void l0_load(short8v* b, const short8v* xs, int c) {
#pragma unroll
  for (int i = 0; i < 8; ++i) b[i] = xs[(c * 8 + i) * 4];
}
__device__ __forceinline__ void l0_comp(const short8v* b, const short8v* afr, int c,
                                        float4v& acc0, float4v& acc1) {
#pragma unroll
  for (int i = 0; i < 8; ++i) {
    const int kt = c * 8 + i;
    if (i & 1)
      acc1 = __builtin_amdgcn_mfma_f32_16x16x32_bf16(afr[kt], b[i], acc1, 0, 0, 0);
    else
      acc0 = __builtin_amdgcn_mfma_f32_16x16x32_bf16(afr[kt], b[i], acc0, 0, 0, 0);
  }
}
__device__ __forceinline__ void l1_load(short8v* bx, short8v* bh,
                                        const short8v* xs, const short8v* hs, int c) {
#pragma unroll
  for (int i = 0; i < 4; ++i) {
    bx[i] = xs[(c * 4 + i) * 4];
    bh[i] = hs[(c * 4 + i) * 4];
  }
}
__device__ __forceinline__ void l1_comp(const short8v* bx, const short8v* bh,
                                        const short8v* afr, const unsigned short* Wxs,
                                        int m, int q, int c, float4v& acc0, float4v& acc1) {
#pragma unroll
  for (int i = 0; i < 4; ++i) {
    const int kt = c * 4 + i;
    const int qc = kt * 4 + q;
    const int p8 = ((qc & ~7) | ((qc ^ m) & 7)) * 8;
    short8v ax = *reinterpret_cast<const short8v*>(&Wxs[m * 1024 + p8]);
    acc0 = __builtin_amdgcn_mfma_f32_16x16x32_bf16(ax, bx[i], acc0, 0, 0, 0);        // W_ih @ x
    acc1 = __builtin_amdgcn_mfma_f32_16x16x32_bf16(afr[kt], bh[i], acc1, 0, 0, 0);   // W_hh @ h
  }
}

// ---------------- fused pipelined 2-layer recurrence (fence-free) ----------------
// blocks 0..63: layer0 (cols j*16..); blocks 64..127: layer1 (1 step behind).
// X layout: [slot][b][col] bf16; slot 0 = initial hidden, slot t+1 = h after step t.
// Producer side: agent-scope sc1 stores -> vmcnt(0) -> __syncthreads -> tid0 flag.
// Consumer side: wave0 polls flags (s_sleep backoff), barrier, then PLAIN vector
// loads of X. Plain loads are safe: each X line is written exactly once and only
// read after the flag (data drained to coherence point first), so no stale L2
// copy can exist; and plain loads pipeline (atomics serialize in the scheduler).
extern "C" __global__ void __launch_bounds__(256) k_chain(
    const float* __restrict__ whh, const float* __restrict__ wih,
    const float* __restrict__ bih, const float* __restrict__ bhh,
    const float* __restrict__ hidden, const float* __restrict__ pre0,
    unsigned short* __restrict__ X0, unsigned short* __restrict__ X1,
    unsigned int* flags, float* __restrict__ hfin) {
  __shared__ unsigned short Wxs[16 * 1024];  // layer1 W_ih slice (XOR-swizzled)
  const int layer = blockIdx.x >> 6;
  const int j = blockIdx.x & 63;
  const int c0 = j * 16;
  const int tid = threadIdx.x;
  const int lane = tid & 63;
  const int wv = tid >> 6;
  const int m = lane & 15;        // A-frag row (weight out-col); B-frag row (batch)
  const int q = lane >> 4;        // quad -> k-chunk / C-row group
  const int brow = wv * 16 + m;   // batch row this lane loads/stores
  const int csub = q * 4;         // 4 consecutive output cols per lane (C rows)

  // ---- hoist recurrent-W A-fragments into registers (step-invariant) ----
  short8v afr[32];
  {
    const float* wrec = whh + (size_t)layer * Hh * Hh + (size_t)(c0 + m) * Hh + q * 8;
#pragma unroll
    for (int kt = 0; kt < 32; ++kt) {
      union { ushort4v h[2]; short8v v; } u;
      float4v w0 = *reinterpret_cast<const float4v*>(wrec + kt * 32);
      float4v w1 = *reinterpret_cast<const float4v*>(wrec + kt * 32 + 4);
      u.h[0] = cvt4(w0, 1.0f); u.h[1] = cvt4(w1, 1.0f);
      afr[kt] = u.v;
    }
  }
  // ---- layer1: stage W_ih slice in LDS (swizzle: 2-way banks, free) ----
  if (layer) {
#pragma unroll
    for (int i = 0; i < 8; ++i) {
      int c = i * 256 + tid;  // 2048 chunks of 8 elems
      int row = c >> 7, qq = c & 127;
      int p = (qq & ~7) | ((qq ^ row) & 7);
      const float* sx = wih + (size_t)Hh * Ee + (size_t)(c0 + row) * Ee + qq * 8;
      float4v u0 = *reinterpret_cast<const float4v*>(sx);
      float4v u1 = *reinterpret_cast<const float4v*>(sx + 4);
      *reinterpret_cast<ushort4v*>(&Wxs[row * 1024 + p * 8]) = cvt4(u0, 1.0f);
      *reinterpret_cast<ushort4v*>(&Wxs[row * 1024 + p * 8 + 4]) = cvt4(u1, 1.0f);
    }
  }
  __syncthreads();

  float4v bias4;
  {
    float4v b1 = *reinterpret_cast<const float4v*>(bih + (size_t)layer * Hh + c0 + csub);
    float4v b2 = *reinterpret_cast<const float4v*>(bhh + (size_t)layer * Hh + c0 + csub);
    bias4 = b1 + b2;
  }
  unsigned short* Xown = layer ? X1 : X0;

  // ---- init slot 0 from `hidden` ----
  {
    float4v h0 = *reinterpret_cast<const float4v*>(hidden + ((size_t)layer * Bb + brow) * Hh + c0 + csub);
    ull pk = (ull)f2bf(h0.x) | ((ull)f2bf(h0.y) << 16) | ((ull)f2bf(h0.z) << 32) | ((ull)f2bf(h0.w) << 48);
    ast((ull*)(Xown + (size_t)brow * Hh + c0 + csub), pk);
  }
  asm volatile("s_waitcnt vmcnt(0)" ::: "memory");
  __syncthreads();  // all 4 waves' slot-0 stores drained
  if (tid == 0)
    fst(&flags[((size_t)layer * (Ss + 1)) * 64 + j], 1u);

  for (int t = 0; t < Ss; ++t) {
    // ---- wave 0 polls producer flags (with backoff); others wait at barrier ----
    if (wv == 0) {
      if (layer == 0) {
        const unsigned* f = flags + (size_t)t * 64;
        int sp = 0;
        for (;;) {
          unsigned v = fld(&f[lane]);
          if (!__any(v == 0)) break;
          if (++sp > (1 << 20)) break;
          __builtin_amdgcn_s_sleep(2);
        }
      } else {
        const unsigned* fa = flags + (size_t)(t + 1) * 64;               // layer0 slot t+1
        const unsigned* fb = flags + ((size_t)(Ss + 1) + t) * 64;        // layer1 slot t
        int sp = 0;
        for (;;) {
          unsigned va = fld(&fa[lane]);
          unsigned vb = fld(&fb[lane]);
          if (!__any((va == 0) | (vb == 0))) break;
          if (++sp > (1 << 20)) break;
          __builtin_amdgcn_s_sleep(2);
        }
      }
    }
    __syncthreads();                // release waves 1..3 once flags observed
    asm volatile("" ::: "memory");  // keep data loads after the poll/barrier

    float4v acc0 = {0.f, 0.f, 0.f, 0.f}, acc1 = {0.f, 0.f, 0.f, 0.f};
    if (layer == 0) {
      const short8v* xs = reinterpret_cast<const short8v*>(
          X0 + (size_t)t * Bb * Hh + (size_t)brow * Hh) + q;
      short8v A0[8], B0[8];
      l0_load(A0, xs, 0);
      l0_load(B0, xs, 1);
      l0_comp(A0, afr, 0, acc0, acc1);
      l0_load(A0, xs, 2);
      l0_comp(B0, afr, 1, acc0, acc1);
      l0_load(B0, xs, 3);
      l0_comp(A0, afr, 2, acc0, acc1);
      l0_comp(B0, afr, 3, acc0, acc1);
    } else {
      const short8v* xs = reinterpret_cast<const short8v*>(
          X0 + (size_t)(t + 1) * Bb * Hh + (size_t)brow * Hh) + q;
      const short8v* hs = reinterpret_cast<const short8v*>(
          X1 + (size_t)t * Bb * Hh + (size_t)brow * Hh) + q;
      short8v Ax[4], Ah[4], Bx[4], Bh[4];
      l1_load(Ax, Ah, xs, hs, 0);
      l1_load(Bx, Bh, xs, hs, 1);
      l1_comp(Ax, Ah, afr, Wxs, m, q, 0, acc0, acc1);
      l1_load(Ax, Ah, xs, hs, 2);
      l1_comp(Bx, Bh, afr, Wxs, m, q, 1, acc0, acc1);
      l1_load(Bx, Bh, xs, hs, 3);
      l1_comp(Ax, Ah, afr, Wxs, m, q, 2, acc0, acc1);
      l1_load(Ax, Ah, xs, hs, 4);
      l1_comp(Bx, Bh, afr, Wxs, m, q, 3, acc0, acc1);
      l1_load(Bx, Bh, xs, hs, 5);
      l1_comp(Ax, Ah, afr, Wxs, m, q, 4, acc0, acc1);
      l1_load(Ax, Ah, xs, hs, 6);
      l1_comp(Bx, Bh, afr, Wxs, m, q, 5, acc0, acc1);
      l1_load(Bx, Bh, xs, hs, 7);
      l1_comp(Ax, Ah, afr, Wxs, m, q, 6, acc0, acc1);
      l1_comp(Bx, Bh, afr, Wxs, m, q, 7, acc0, acc1);
    }

    float4v r = acc0 + acc1 + bias4;
    if (layer == 0) {
      float4v pz = *reinterpret_cast<const float4v*>(pre0 + ((size_t)t * Bb + brow) * Hh + c0 + csub);
      r += pz;
    }
    float h0 = fast_tanh(r.x), h1 = fast_tanh(r.y), h2 = fast_tanh(r.z), h3 = fast_tanh(r.w);
    if (t == Ss - 1) {
      float4v hf = {h0, h1, h2, h3};
      *reinterpret_cast<float4v*>(hfin + ((size_t)layer * Bb + brow) * Hh + c0 + csub) = hf;
    }
    ull pk = (ull)f2bf(h0) | ((ull)f2bf(h1) << 16) | ((ull)f2bf(h2) << 32) | ((ull)f2bf(h3) << 48);
    ast((ull*)(Xown + ((size_t)(t + 1) * Bb + brow) * Hh + c0 + csub), pk);
    asm volatile("s_waitcnt vmcnt(0)" ::: "memory");  // data at coherence point
    __syncthreads();                                  // ... for ALL waves of the block
    if (tid == 0)
      fst(&flags[((size_t)layer * (Ss + 1) + (t + 1)) * 64 + j], 1u);
  }
}

// ---------------- logits = X1 @ Wout^T + b_out ----------------
extern "C" __global__ void __launch_bounds__(256) k_gemm_logits(
    const unsigned short* __restrict__ Abf, const unsigned short* __restrict__ Bbf,
    const float* __restrict__ bout, float* __restrict__ out) {
  __shared__ unsigned short As[128 * 32];
  __shared__ unsigned short Bs[128 * 32];
  const int m0 = blockIdx.x * 128;
  const int n0 = blockIdx.y * 128;
  const int tid = threadIdx.x;
  const int lane = tid & 63;
  const int wv = tid >> 6;
  const int wm = wv & 1, wn = wv >> 1;
  float4v acc[4][4] = {};
  for (int k0 = 0; k0 < Hh; k0 += 32) {
    __syncthreads();
#pragma unroll
    for (int i = 0; i < 2; ++i) {  // async stage 16B/lane; base wave-uniform
      int c = (wv * 2 + i) * 64 + lane;  // 0..511 chunks of 8 elems
      int r = c >> 2, q = c & 3;
      gload_lds16(Abf + (size_t)(m0 + r) * Hh + k0 + q * 8, &As[(wv * 2 + i) * 512]);
      gload_lds16(Bbf + (size_t)(n0 + r) * Hh + k0 + q * 8, &Bs[(wv * 2 + i) * 512]);
    }
    __syncthreads();
    short8v af[4], bf[4];
#pragma unroll
    for (int i = 0; i < 4; ++i) {
      af[i] = *reinterpret_cast<const short8v*>(&As[(wm * 64 + i * 16 + (lane & 15)) * 32 + (lane >> 4) * 8]);
      bf[i] = *reinterpret_cast<const short8v*>(&Bs[(wn * 64 + i * 16 + (lane & 15)) * 32 + (lane >> 4) * 8]);
    }
#pragma unroll
    for (int mi = 0; mi < 4; ++mi)
#pragma unroll
      for (int ni = 0; ni < 4; ++ni)
        acc[mi][ni] = __builtin_amdgcn_mfma_f32_16x16x32_bf16(af[mi], bf[ni], acc[mi][ni], 0, 0, 0);
  }
#pragma unroll
  for (int mi = 0; mi < 4; ++mi) {
    const int rb = m0 + wm * 64 + mi * 16 + ((lane >> 4) << 2);
#pragma unroll
    for (int ni = 0; ni < 4; ++ni) {
      const int col = n0 + wn * 64 + ni * 16 + (lane & 15);
      if (col < Vv) {
        const float bz = bout[col];
#pragma unroll
        for (int r = 0; r < 4; ++r)
          out[(size_t)(rb + r) * Vv + col] = acc[mi][ni][r] + bz;
      }
    }
  }
}

extern "C" void kernel_launch(void* const* d_in, const int* in_sizes, int n_in,
                              void* d_out, int out_size, void* d_ws, size_t ws_size,
                              hipStream_t stream) {
  (void)in_sizes; (void)n_in; (void)out_size; (void)ws_size;
  const int* tok = (const int*)d_in[0];
  const float* hidden = (const float*)d_in[1];
  const float* emb = (const float*)d_in[2];
  const float* wih = (const float*)d_in[3];
  const float* bih = (const float*)d_in[4];
  const float* whh = (const float*)d_in[5];
  const float* bhh = (const float*)d_in[6];
  const float* wout = (const float*)d_in[7];
  const float* bout = (const float*)d_in[8];
  float* out = (float*)d_out;

  char* ws = (char*)d_ws;
  size_t off = 0;
  auto walloc = [&](size_t b) { void* p = ws + off; off = (off + b + 255) & ~(size_t)255; return p; };
  unsigned short* X0 = (unsigned short*)walloc((size_t)(Ss + 1) * Bb * Hh * 2);  // 16.9 MB
  unsigned short* X1 = (unsigned short*)walloc((size_t)(Ss + 1) * Bb * Hh * 2);  // 16.9 MB
  float* pre0 = (float*)walloc((size_t)Ss * Bb * Hh * 4);                        // 33.6 MB
  unsigned short* wob = (unsigned short*)walloc((size_t)NPAD * Hh * 2);          // 20.7 MB
  const size_t flag_bytes = (size_t)2 * (Ss + 1) * 64 * 4;                       // 66 KB
  unsigned int* flags = (unsigned int*)walloc(flag_bytes);

  hipMemsetAsync(flags, 0, flag_bytes, stream);  // ws is poisoned 0xAA each run
  k_conv_wout<<<NPAD, 256, 0, stream>>>(wout, wob);
  k_gemm_pre0<<<dim3(64, 8), 256, 0, stream>>>(tok, emb, wih, pre0);
  k_chain<<<128, 256, 0, stream>>>(whh, wih, bih, bhh, hidden, pre0, X0, X1, flags,
                                   out + (size_t)Ss * Bb * Vv);
  k_gemm_logits<<<dim3(64, 79), 256, 0, stream>>>(X1 + (size_t)Bb * Hh, wob, bout, out);
}